// Round 2
// baseline (68432.233 us; speedup 1.0000x reference)
//
#include <hip/hip_runtime.h>
#include <hip/hip_cooperative_groups.h>
#include <cstdint>
#include <cstddef>

namespace cg = cooperative_groups;

static constexpr int BATCH   = 128;
static constexpr int TSTEPS  = 512;
static constexpr int NBLOCKS = 244;   // <= 256 CUs -> co-residency guaranteed
static constexpr int NT      = 256;

// block role ranges
static constexpr int NB1 = 80, NB2 = 100, NB3 = 32, NB4 = 32;
static constexpr int RB1 = 0, RB2 = NB1, RB3 = NB1 + NB2, RB4 = NB1 + NB2 + NB3;

// ---------------- workspace layout (float offsets) ----------------
static constexpr size_t O_XT  = 0;                         // [512][64][128]
static constexpr size_t SZ_XT = 512ull * 64 * 128;         // 4,194,304
static constexpr size_t O_H1  = O_XT + SZ_XT;              // 2 parities x [640][128]
static constexpr size_t O_H2  = O_H1 + 2ull * 640 * 128;
static constexpr size_t O_H3  = O_H2 + 2ull * 400 * 128;
static constexpr size_t O_H4  = O_H3 + 2ull * 256 * 128;
static constexpr size_t O_HEND= O_H4 + 2ull * 256 * 128;
static constexpr size_t HTOT  = O_HEND - O_H1;             // 397,312 floats
static constexpr size_t O_PK1 = O_HEND;                    // 80*704*8*4
static constexpr size_t O_PK2 = O_PK1 + 80ull  * 704  * 8 * 4;
static constexpr size_t O_PK3 = O_PK2 + 100ull * 1040 * 4 * 4;
static constexpr size_t O_PK4 = O_PK3 + 32ull  * 656  * 8 * 4;
// end = O_PK4 + 32*512*8*4 = 9,253,888 floats = 37.0 MB

struct KParams {
  const float *x;
  const float *k1, *r1, *b1, *k2, *r2, *b2, *k3, *r3, *b3, *k4, *r4, *b4;
  const float *wd1, *bd1, *wd2, *bd2, *wd3, *bd3, *wd4, *bd4, *wd5, *bd5, *wd6, *bd6;
  float *out;
  float *ws;
};

__device__ __forceinline__ void fma4(float4& a, float s, const float4& w) {
  a.x += s * w.x; a.y += s * w.y; a.z += s * w.z; a.w += s * w.w;
}
__device__ __forceinline__ float sigm(float v) { return 1.f / (1.f + expf(-v)); }

// ---------------- weight prepack: pack[blk][k][quad][gate] ----------------
__device__ void prepack_layer(const float* __restrict__ gk, const float* __restrict__ gr,
                              float* __restrict__ pack, int DIN, int H, int NJ, int NBLK,
                              int gtid, int gstr) {
  const long K = DIN + H;
  const long total = (long)NBLK * K * NJ * 4;
  for (long e = gtid; e < total; e += gstr) {
    int  g   = (int)(e & 3);
    long r   = e >> 2;
    int  q   = (int)(r % NJ);
    long r2  = r / NJ;
    int  k   = (int)(r2 % K);
    int  blk = (int)(r2 / K);
    int  j   = blk * NJ + q;
    float v = (k < DIN) ? gk[(size_t)k * 4 * H + (size_t)g * H + j]
                        : gr[(size_t)(k - DIN) * 4 * H + (size_t)g * H + j];
    pack[e] = v;
  }
}

// ---------------- persistent LSTM layer role ----------------
// MB=8 batch rows/thread, BG=16 batch-groups, threads = BG*NJ*KS = 256.
template<int DIN, int H, int NJ, int KS, int LOFF, bool SEQIN>
__device__ void lstm_role(cg::grid_group& grid, int blk,
                          const float* __restrict__ xT,     // SEQIN input [T][DIN][128]
                          const float* __restrict__ inH,    // lower-layer parity pair base
                          float* __restrict__ ownH,         // own parity pair base
                          const float* __restrict__ pack,
                          const float* __restrict__ gbias,
                          float* smem) {
  constexpr int K   = DIN + H;
  constexpr int MB  = 8;
  constexpr int BG  = BATCH / MB;        // 16
  constexpr int NTK = BG * NJ;
  static_assert(NTK * KS == NT, "bad thread split");
  static_assert(K % KS == 0, "K % KS");
  constexpr int KC  = K / KS;

  const int tid = threadIdx.x;
  const int ks  = tid / NTK;
  const int tin = tid % NTK;
  const int jj  = tin / BG;
  const int bg  = tin % BG;
  const int b0  = bg * MB;
  const int j   = blk * NJ + jj;

  const float* mypack = pack + (size_t)blk * K * NJ * 4;
  float4 bias = make_float4(gbias[j], gbias[H + j], gbias[2 * H + j], gbias[3 * H + j]);

  float c[MB];
  #pragma unroll
  for (int m = 0; m < MB; ++m) c[m] = 0.f;

  float4* part4 = (float4*)smem;         // [(KS-1)*NTK][8]

  const int kbeg   = ks * KC, kend = kbeg + KC;
  const int kx_end = (kbeg < DIN) ? ((kend < DIN) ? kend : DIN) : kbeg;
  const int kh_beg = (kbeg > DIN) ? kbeg : DIN;

  for (int s = 0; s < TSTEPS + 3; ++s) {
    const int t = s - LOFF;
    if (t >= 0 && t < TSTEPS) {
      const float* in_t  = SEQIN ? (xT + (size_t)t * DIN * BATCH)
                                 : (inH + (size_t)((s - 1) & 1) * DIN * BATCH);
      const float* hprev = ownH + (size_t)((s - 1) & 1) * H * BATCH;
      float*       hnext = ownH + (size_t)(s & 1) * H * BATCH;

      float4 a[MB];
      #pragma unroll
      for (int m = 0; m < MB; ++m) a[m] = make_float4(0.f, 0.f, 0.f, 0.f);

      #pragma unroll 4
      for (int k = kbeg; k < kx_end; ++k) {
        float4 hv1 = *(const float4*)(in_t + (size_t)k * BATCH + b0);
        float4 hv2 = *(const float4*)(in_t + (size_t)k * BATCH + b0 + 4);
        float4 w   = *(const float4*)(mypack + ((size_t)k * NJ + jj) * 4);
        fma4(a[0], hv1.x, w); fma4(a[1], hv1.y, w); fma4(a[2], hv1.z, w); fma4(a[3], hv1.w, w);
        fma4(a[4], hv2.x, w); fma4(a[5], hv2.y, w); fma4(a[6], hv2.z, w); fma4(a[7], hv2.w, w);
      }
      #pragma unroll 4
      for (int k = kh_beg; k < kend; ++k) {
        float4 hv1 = *(const float4*)(hprev + (size_t)(k - DIN) * BATCH + b0);
        float4 hv2 = *(const float4*)(hprev + (size_t)(k - DIN) * BATCH + b0 + 4);
        float4 w   = *(const float4*)(mypack + ((size_t)k * NJ + jj) * 4);
        fma4(a[0], hv1.x, w); fma4(a[1], hv1.y, w); fma4(a[2], hv1.z, w); fma4(a[3], hv1.w, w);
        fma4(a[4], hv2.x, w); fma4(a[5], hv2.y, w); fma4(a[6], hv2.z, w); fma4(a[7], hv2.w, w);
      }

      if (KS > 1) {
        if (ks > 0) {
          float4* p = part4 + ((size_t)(ks - 1) * NTK + tin) * 8;
          #pragma unroll
          for (int m = 0; m < MB; ++m) p[m] = a[m];
        }
        __syncthreads();
        if (ks == 0) {
          #pragma unroll
          for (int s2 = 1; s2 < KS; ++s2) {
            const float4* p = part4 + ((size_t)(s2 - 1) * NTK + tin) * 8;
            #pragma unroll
            for (int m = 0; m < MB; ++m) {
              a[m].x += p[m].x; a[m].y += p[m].y; a[m].z += p[m].z; a[m].w += p[m].w;
            }
          }
        }
      }

      if (ks == 0) {
        float hv[MB];
        #pragma unroll
        for (int m = 0; m < MB; ++m) {
          float ig = sigm(a[m].x + bias.x);
          float fg = sigm(a[m].y + bias.y);
          float gg = tanhf(a[m].z + bias.z);
          float og = sigm(a[m].w + bias.w);
          c[m] = fg * c[m] + ig * gg;
          hv[m] = og * tanhf(c[m]);
        }
        *(float4*)(hnext + (size_t)j * BATCH + b0)     = make_float4(hv[0], hv[1], hv[2], hv[3]);
        *(float4*)(hnext + (size_t)j * BATCH + b0 + 4) = make_float4(hv[4], hv[5], hv[6], hv[7]);
      }
    }
    grid.sync();
  }
}

// ---------------- dense head helpers ----------------
__device__ void dense_stage(const float* in, float* outb,
                            const float* __restrict__ w, const float* __restrict__ bias,
                            int din, int dout, bool relu) {
  for (int jc = threadIdx.x; jc < dout; jc += NT) {
    float s = bias[jc];
    for (int d = 0; d < din; ++d) s += in[d] * w[(size_t)d * dout + jc];
    outb[jc] = relu ? fmaxf(s, 0.f) : s;
  }
  __syncthreads();
}

// ---------------- the fused cooperative kernel ----------------
__global__ __launch_bounds__(NT) void fused_kernel(KParams p) {
  cg::grid_group grid = cg::this_grid();
  __shared__ alignas(16) char smem_raw[33280];
  float* smem = (float*)smem_raw;

  float* ws  = p.ws;
  const int tid  = threadIdx.x;
  const int bid  = blockIdx.x;
  const int gtid = bid * NT + tid;
  const int gstr = NBLOCKS * NT;

  // ---- phase 0a: zero all h parity buffers (h_{-1} = 0 for every layer) ----
  {
    float* hb = ws + O_H1;
    for (size_t i = gtid; i < HTOT; i += gstr) hb[i] = 0.f;
  }
  // ---- phase 0b: prepack weights into per-block contiguous streams ----
  prepack_layer(p.k1, p.r1, ws + O_PK1, 64,  640, 8, NB1, gtid, gstr);
  prepack_layer(p.k2, p.r2, ws + O_PK2, 640, 400, 4, NB2, gtid, gstr);
  prepack_layer(p.k3, p.r3, ws + O_PK3, 400, 256, 8, NB3, gtid, gstr);
  prepack_layer(p.k4, p.r4, ws + O_PK4, 256, 256, 8, NB4, gtid, gstr);
  // ---- phase 0c: transpose x [128][512][64] -> xT [512][64][128] ----
  {
    float* tile = smem;                 // [64][129] padded
    float* xT   = ws + O_XT;
    for (int t = bid; t < TSTEPS; t += NBLOCKS) {
      // load: thread covers row b=tid/2, cols d = (tid%2)*32 .. +31
      int b = tid >> 1, dbase = (tid & 1) * 32;
      const float* src = p.x + ((size_t)b * TSTEPS + t) * 64 + dbase;
      #pragma unroll
      for (int q = 0; q < 8; ++q) {
        float4 v = *(const float4*)(src + 4 * q);
        tile[(dbase + 4 * q + 0) * 129 + b] = v.x;
        tile[(dbase + 4 * q + 1) * 129 + b] = v.y;
        tile[(dbase + 4 * q + 2) * 129 + b] = v.z;
        tile[(dbase + 4 * q + 3) * 129 + b] = v.w;
      }
      __syncthreads();
      // store: thread covers d=tid/4, b = (tid%4)*32 .. +31
      int d = tid >> 2, bb = (tid & 3) * 32;
      float* dst = xT + ((size_t)t * 64 + d) * BATCH + bb;
      #pragma unroll
      for (int q = 0; q < 8; ++q) {
        float4 v = make_float4(tile[d * 129 + bb + 4 * q + 0],
                               tile[d * 129 + bb + 4 * q + 1],
                               tile[d * 129 + bb + 4 * q + 2],
                               tile[d * 129 + bb + 4 * q + 3]);
        *(float4*)(dst + 4 * q) = v;
      }
      __syncthreads();
    }
  }

  grid.sync();

  // ---- phase 1: pipelined 4-layer LSTM scan (515 steps) ----
  if (bid < RB2) {
    lstm_role<64, 640, 8, 2, 0, true >(grid, bid,        ws + O_XT, nullptr,    ws + O_H1, ws + O_PK1, p.b1, smem);
  } else if (bid < RB3) {
    lstm_role<640, 400, 4, 4, 1, false>(grid, bid - RB2, nullptr,   ws + O_H1,  ws + O_H2, ws + O_PK2, p.b2, smem);
  } else if (bid < RB4) {
    lstm_role<400, 256, 8, 2, 2, false>(grid, bid - RB3, nullptr,   ws + O_H2,  ws + O_H3, ws + O_PK3, p.b3, smem);
  } else {
    lstm_role<256, 256, 8, 2, 3, false>(grid, bid - RB4, nullptr,   ws + O_H3,  ws + O_H4, ws + O_PK4, p.b4, smem);
  }

  // ---- phase 2: dense head, one block per batch row (h4 final is parity 0) ----
  if (bid < BATCH) {
    const int b = bid;
    float* A = smem;
    float* B = smem + 512;
    const float* h4 = ws + O_H4;       // parity 0
    for (int d = tid; d < 256; d += NT) A[d] = h4[(size_t)d * BATCH + b];
    __syncthreads();
    dense_stage(A, B, p.wd1, p.bd1, 256, 512, true);
    dense_stage(B, A, p.wd2, p.bd2, 512, 256, true);
    dense_stage(A, B, p.wd3, p.bd3, 256, 128, true);
    dense_stage(B, A, p.wd4, p.bd4, 128, 64,  true);
    dense_stage(A, B, p.wd5, p.bd5, 64,  16,  true);
    dense_stage(B, A, p.wd6, p.bd6, 16,  3,   false);
    if (tid == 0) {
      float z0 = A[0], z1 = A[1], z2 = A[2];
      float m  = fmaxf(fmaxf(z0, z1), z2);
      float e0 = expf(z0 - m), e1 = expf(z1 - m), e2 = expf(z2 - m);
      float s  = e0 + e1 + e2;
      p.out[b * 3 + 0] = e0 / s;
      p.out[b * 3 + 1] = e1 / s;
      p.out[b * 3 + 2] = e2 / s;
    }
  }
}

// ---------------- launch ----------------
extern "C" void kernel_launch(void* const* d_in, const int* in_sizes, int n_in,
                              void* d_out, int out_size, void* d_ws, size_t ws_size,
                              hipStream_t stream) {
  KParams prm;
  prm.x  = (const float*)d_in[0];
  prm.k1 = (const float*)d_in[1];  prm.r1 = (const float*)d_in[2];  prm.b1 = (const float*)d_in[3];
  prm.k2 = (const float*)d_in[4];  prm.r2 = (const float*)d_in[5];  prm.b2 = (const float*)d_in[6];
  prm.k3 = (const float*)d_in[7];  prm.r3 = (const float*)d_in[8];  prm.b3 = (const float*)d_in[9];
  prm.k4 = (const float*)d_in[10]; prm.r4 = (const float*)d_in[11]; prm.b4 = (const float*)d_in[12];
  prm.wd1 = (const float*)d_in[13]; prm.bd1 = (const float*)d_in[14];
  prm.wd2 = (const float*)d_in[15]; prm.bd2 = (const float*)d_in[16];
  prm.wd3 = (const float*)d_in[17]; prm.bd3 = (const float*)d_in[18];
  prm.wd4 = (const float*)d_in[19]; prm.bd4 = (const float*)d_in[20];
  prm.wd5 = (const float*)d_in[21]; prm.bd5 = (const float*)d_in[22];
  prm.wd6 = (const float*)d_in[23]; prm.bd6 = (const float*)d_in[24];
  prm.out = (float*)d_out;
  prm.ws  = (float*)d_ws;

  void* args[] = { &prm };
  hipLaunchCooperativeKernel((void*)fused_kernel, dim3(NBLOCKS), dim3(NT),
                             args, 0, stream);
}

// Round 3
// 62263.910 us; speedup vs baseline: 1.0991x; 1.0991x over previous
//
#include <hip/hip_runtime.h>
#include <hip/hip_cooperative_groups.h>
#include <cstdint>
#include <cstddef>

namespace cg = cooperative_groups;

static constexpr int BATCH   = 128;
static constexpr int TSTEPS  = 512;
static constexpr int NBLOCKS = 244;   // <= 256 CUs -> co-residency guaranteed
static constexpr int NT      = 256;

// block role ranges
static constexpr int NB1 = 80, NB2 = 100, NB3 = 32, NB4 = 32;
static constexpr int RB2 = NB1, RB3 = NB1 + NB2, RB4 = NB1 + NB2 + NB3;

// ---------------- workspace layout (float offsets) ----------------
static constexpr size_t O_XT  = 0;                         // [512][64][128]
static constexpr size_t SZ_XT = 512ull * 64 * 128;         // 4,194,304
static constexpr size_t O_H1  = O_XT + SZ_XT;              // 2 parities x [640][128]
static constexpr size_t O_H2  = O_H1 + 2ull * 640 * 128;
static constexpr size_t O_H3  = O_H2 + 2ull * 400 * 128;
static constexpr size_t O_H4  = O_H3 + 2ull * 256 * 128;
static constexpr size_t O_HEND= O_H4 + 2ull * 256 * 128;
static constexpr size_t HTOT  = O_HEND - O_H1;             // 397,312 floats
static constexpr size_t O_PK1 = O_HEND;
static constexpr size_t O_PK2 = O_PK1 + 80ull  * 704  * 8 * 4;
static constexpr size_t O_PK3 = O_PK2 + 100ull * 1040 * 4 * 4;
static constexpr size_t O_PK4 = O_PK3 + 32ull  * 656  * 8 * 4;
static constexpr size_t O_CTR = O_PK4 + 32ull  * 512  * 8 * 4;  // 9,253,888 (floats)
// ws bytes = O_CTR*4 + 64 ~= 37.0 MB

struct KParams {
  const float *x;
  const float *k1, *r1, *b1, *k2, *r2, *b2, *k3, *r3, *b3, *k4, *r4, *b4;
  const float *wd1, *bd1, *wd2, *bd2, *wd3, *bd3, *wd4, *bd4, *wd5, *bd5, *wd6, *bd6;
  float *out;
  float *ws;
};

__device__ __forceinline__ void fma4(float4& a, float s, const float4& w) {
  a.x += s * w.x; a.y += s * w.y; a.z += s * w.z; a.w += s * w.w;
}
__device__ __forceinline__ float sigm(float v) { return 1.f / (1.f + expf(-v)); }

// ---- coherent (agent-scope, no-L2-flush) h exchange ----
__device__ __forceinline__ void h_store2(float* p, float a, float b) {
  union { float f[2]; unsigned long long u; } v; v.f[0] = a; v.f[1] = b;
  __hip_atomic_store((unsigned long long*)p, v.u, __ATOMIC_RELAXED, __HIP_MEMORY_SCOPE_AGENT);
}
__device__ __forceinline__ float2 h_load2(const float* p) {
  union { float f[2]; unsigned long long u; } v;
  v.u = __hip_atomic_load((const unsigned long long*)p, __ATOMIC_RELAXED, __HIP_MEMORY_SCOPE_AGENT);
  return make_float2(v.f[0], v.f[1]);
}
__device__ __forceinline__ float h_load1(const float* p) {
  return __hip_atomic_load(p, __ATOMIC_RELAXED, __HIP_MEMORY_SCOPE_AGENT);
}

// ---- light grid barrier: one atomicAdd/block + relaxed poll; no cache flush ----
__device__ __forceinline__ void light_barrier(unsigned* ctr, unsigned target) {
  asm volatile("s_waitcnt vmcnt(0)" ::: "memory");   // this thread's h stores drained
  __syncthreads();                                   // whole block's stores drained
  if (threadIdx.x == 0) {
    __hip_atomic_fetch_add(ctr, 1u, __ATOMIC_RELAXED, __HIP_MEMORY_SCOPE_AGENT);
    while (__hip_atomic_load(ctr, __ATOMIC_RELAXED, __HIP_MEMORY_SCOPE_AGENT) < target) {
      __builtin_amdgcn_s_sleep(2);
    }
  }
  __syncthreads();
}

// ---------------- weight prepack: pack[blk][k][quad][gate] ----------------
__device__ void prepack_layer(const float* __restrict__ gk, const float* __restrict__ gr,
                              float* __restrict__ pack, int DIN, int H, int NJ, int NBLK,
                              int gtid, int gstr) {
  const long K = DIN + H;
  const long total = (long)NBLK * K * NJ * 4;
  for (long e = gtid; e < total; e += gstr) {
    int  g   = (int)(e & 3);
    long r   = e >> 2;
    int  q   = (int)(r % NJ);
    long r2  = r / NJ;
    int  k   = (int)(r2 % K);
    int  blk = (int)(r2 / K);
    int  j   = blk * NJ + q;
    float v = (k < DIN) ? gk[(size_t)k * 4 * H + (size_t)g * H + j]
                        : gr[(size_t)(k - DIN) * 4 * H + (size_t)g * H + j];
    pack[e] = v;
  }
}

// ---------------- persistent LSTM layer role ----------------
template<int DIN, int H, int NJ, int KS, int LOFF, bool SEQIN>
__device__ void lstm_role(int blk,
                          const float* __restrict__ xT,
                          const float* __restrict__ inH,
                          float* __restrict__ ownH,
                          const float* __restrict__ pack,
                          const float* __restrict__ gbias,
                          float* smem, unsigned* ctr) {
  constexpr int K   = DIN + H;
  constexpr int MB  = 8;
  constexpr int BG  = BATCH / MB;        // 16
  constexpr int NTK = BG * NJ;
  static_assert(NTK * KS == NT, "bad thread split");
  static_assert(K % KS == 0, "K % KS");
  constexpr int KC  = K / KS;

  const int tid = threadIdx.x;
  const int ks  = tid / NTK;
  const int tin = tid % NTK;
  const int jj  = tin / BG;
  const int bg  = tin % BG;
  const int b0  = bg * MB;
  const int j   = blk * NJ + jj;

  const float* mypack = pack + (size_t)blk * K * NJ * 4;
  float4 bias = make_float4(gbias[j], gbias[H + j], gbias[2 * H + j], gbias[3 * H + j]);

  float c[MB];
  #pragma unroll
  for (int m = 0; m < MB; ++m) c[m] = 0.f;

  // partials layout [(ks-1)][mm 0..15][tin] float2 -> lanes 8B apart (conflict-free)
  float2* part2 = (float2*)smem;

  const int kbeg   = ks * KC, kend = kbeg + KC;
  const int kx_end = (kbeg < DIN) ? ((kend < DIN) ? kend : DIN) : kbeg;
  const int kh_beg = (kbeg > DIN) ? kbeg : DIN;

  for (int s = 0; s < TSTEPS + 3; ++s) {
    const int t = s - LOFF;
    if (t >= 0 && t < TSTEPS) {
      const float* hprev = ownH + (size_t)((s - 1) & 1) * H * BATCH;
      float*       hnext = ownH + (size_t)(s & 1) * H * BATCH;

      float4 a[MB];
      #pragma unroll
      for (int m = 0; m < MB; ++m) a[m] = make_float4(0.f, 0.f, 0.f, 0.f);

      if (SEQIN) {
        const float* in_t = xT + (size_t)t * DIN * BATCH;
        #pragma unroll 4
        for (int k = kbeg; k < kx_end; ++k) {
          float4 hv1 = *(const float4*)(in_t + (size_t)k * BATCH + b0);
          float4 hv2 = *(const float4*)(in_t + (size_t)k * BATCH + b0 + 4);
          float4 w   = *(const float4*)(mypack + ((size_t)k * NJ + jj) * 4);
          fma4(a[0], hv1.x, w); fma4(a[1], hv1.y, w); fma4(a[2], hv1.z, w); fma4(a[3], hv1.w, w);
          fma4(a[4], hv2.x, w); fma4(a[5], hv2.y, w); fma4(a[6], hv2.z, w); fma4(a[7], hv2.w, w);
        }
      } else {
        const float* in_t = inH + (size_t)((s - 1) & 1) * DIN * BATCH;
        #pragma unroll 4
        for (int k = kbeg; k < kx_end; ++k) {
          const float* row = in_t + (size_t)k * BATCH + b0;
          float2 p0 = h_load2(row);
          float2 p1 = h_load2(row + 2);
          float2 p2 = h_load2(row + 4);
          float2 p3 = h_load2(row + 6);
          float4 w  = *(const float4*)(mypack + ((size_t)k * NJ + jj) * 4);
          fma4(a[0], p0.x, w); fma4(a[1], p0.y, w); fma4(a[2], p1.x, w); fma4(a[3], p1.y, w);
          fma4(a[4], p2.x, w); fma4(a[5], p2.y, w); fma4(a[6], p3.x, w); fma4(a[7], p3.y, w);
        }
      }
      #pragma unroll 4
      for (int k = kh_beg; k < kend; ++k) {
        const float* row = hprev + (size_t)(k - DIN) * BATCH + b0;
        float2 p0 = h_load2(row);
        float2 p1 = h_load2(row + 2);
        float2 p2 = h_load2(row + 4);
        float2 p3 = h_load2(row + 6);
        float4 w  = *(const float4*)(mypack + ((size_t)k * NJ + jj) * 4);
        fma4(a[0], p0.x, w); fma4(a[1], p0.y, w); fma4(a[2], p1.x, w); fma4(a[3], p1.y, w);
        fma4(a[4], p2.x, w); fma4(a[5], p2.y, w); fma4(a[6], p3.x, w); fma4(a[7], p3.y, w);
      }

      if (KS > 1) {
        if (ks > 0) {
          float2* p = part2 + (size_t)(ks - 1) * 16 * NTK + tin;
          #pragma unroll
          for (int m = 0; m < MB; ++m) {
            p[(2 * m + 0) * NTK] = make_float2(a[m].x, a[m].y);
            p[(2 * m + 1) * NTK] = make_float2(a[m].z, a[m].w);
          }
        }
        __syncthreads();
        if (ks == 0) {
          #pragma unroll
          for (int s2 = 1; s2 < KS; ++s2) {
            const float2* p = part2 + (size_t)(s2 - 1) * 16 * NTK + tin;
            #pragma unroll
            for (int m = 0; m < MB; ++m) {
              float2 u0 = p[(2 * m + 0) * NTK];
              float2 u1 = p[(2 * m + 1) * NTK];
              a[m].x += u0.x; a[m].y += u0.y; a[m].z += u1.x; a[m].w += u1.y;
            }
          }
        }
      }

      if (ks == 0) {
        float hv[MB];
        #pragma unroll
        for (int m = 0; m < MB; ++m) {
          float ig = sigm(a[m].x + bias.x);
          float fg = sigm(a[m].y + bias.y);
          float gg = tanhf(a[m].z + bias.z);
          float og = sigm(a[m].w + bias.w);
          c[m] = fg * c[m] + ig * gg;
          hv[m] = og * tanhf(c[m]);
        }
        float* dst = hnext + (size_t)j * BATCH + b0;
        h_store2(dst + 0, hv[0], hv[1]);
        h_store2(dst + 2, hv[2], hv[3]);
        h_store2(dst + 4, hv[4], hv[5]);
        h_store2(dst + 6, hv[6], hv[7]);
      }
    }
    light_barrier(ctr, (unsigned)(s + 1) * (unsigned)NBLOCKS);
  }
}

// ---------------- dense head helpers ----------------
__device__ void dense_stage(const float* in, float* outb,
                            const float* __restrict__ w, const float* __restrict__ bias,
                            int din, int dout, bool relu) {
  for (int jc = threadIdx.x; jc < dout; jc += NT) {
    float s = bias[jc];
    for (int d = 0; d < din; ++d) s += in[d] * w[(size_t)d * dout + jc];
    outb[jc] = relu ? fmaxf(s, 0.f) : s;
  }
  __syncthreads();
}

// ---------------- the fused cooperative kernel ----------------
__global__ __launch_bounds__(NT) void fused_kernel(KParams p) {
  cg::grid_group grid = cg::this_grid();
  __shared__ alignas(16) char smem_raw[33280];
  float* smem = (float*)smem_raw;

  float* ws  = p.ws;
  unsigned* ctr = (unsigned*)(ws + O_CTR);
  const int tid  = threadIdx.x;
  const int bid  = blockIdx.x;
  const int gtid = bid * NT + tid;
  const int gstr = NBLOCKS * NT;

  // ---- phase 0a: zero all h parity buffers ----
  {
    float* hb = ws + O_H1;
    for (size_t i = gtid; i < HTOT; i += gstr) hb[i] = 0.f;
  }
  // ---- phase 0b: prepack weights ----
  prepack_layer(p.k1, p.r1, ws + O_PK1, 64,  640, 8, NB1, gtid, gstr);
  prepack_layer(p.k2, p.r2, ws + O_PK2, 640, 400, 4, NB2, gtid, gstr);
  prepack_layer(p.k3, p.r3, ws + O_PK3, 400, 256, 8, NB3, gtid, gstr);
  prepack_layer(p.k4, p.r4, ws + O_PK4, 256, 256, 8, NB4, gtid, gstr);
  // ---- phase 0c: transpose x [128][512][64] -> xT [512][64][128] ----
  {
    float* tile = smem;                 // [64][129] padded
    float* xT   = ws + O_XT;
    for (int t = bid; t < TSTEPS; t += NBLOCKS) {
      int b = tid >> 1, dbase = (tid & 1) * 32;
      const float* src = p.x + ((size_t)b * TSTEPS + t) * 64 + dbase;
      #pragma unroll
      for (int q = 0; q < 8; ++q) {
        float4 v = *(const float4*)(src + 4 * q);
        tile[(dbase + 4 * q + 0) * 129 + b] = v.x;
        tile[(dbase + 4 * q + 1) * 129 + b] = v.y;
        tile[(dbase + 4 * q + 2) * 129 + b] = v.z;
        tile[(dbase + 4 * q + 3) * 129 + b] = v.w;
      }
      __syncthreads();
      int d = tid >> 2, bb = (tid & 3) * 32;
      float* dst = xT + ((size_t)t * 64 + d) * BATCH + bb;
      #pragma unroll
      for (int q = 0; q < 8; ++q) {
        float4 v = make_float4(tile[d * 129 + bb + 4 * q + 0],
                               tile[d * 129 + bb + 4 * q + 1],
                               tile[d * 129 + bb + 4 * q + 2],
                               tile[d * 129 + bb + 4 * q + 3]);
        *(float4*)(dst + 4 * q) = v;
      }
      __syncthreads();
    }
  }

  // ONE full CG sync: publishes xT/packs/zeroed-h everywhere (incl. L2 writeback)
  grid.sync();

  // ---- phase 1: pipelined 4-layer LSTM scan ----
  if (bid < RB2) {
    lstm_role<64, 640, 8, 2, 0, true >(bid,       ws + O_XT, nullptr,   ws + O_H1, ws + O_PK1, p.b1, smem, ctr);
  } else if (bid < RB3) {
    lstm_role<640, 400, 4, 4, 1, false>(bid - RB2, nullptr,  ws + O_H1, ws + O_H2, ws + O_PK2, p.b2, smem, ctr);
  } else if (bid < RB4) {
    lstm_role<400, 256, 8, 2, 2, false>(bid - RB3, nullptr,  ws + O_H2, ws + O_H3, ws + O_PK3, p.b3, smem, ctr);
  } else {
    lstm_role<256, 256, 8, 2, 3, false>(bid - RB4, nullptr,  ws + O_H3, ws + O_H4, ws + O_PK4, p.b4, smem, ctr);
  }

  // ---- phase 2: dense head (h4 final is parity 0; read agent-scope) ----
  if (bid < BATCH) {
    const int b = bid;
    float* A = smem;
    float* B = smem + 512;
    const float* h4 = ws + O_H4;
    for (int d = tid; d < 256; d += NT) A[d] = h_load1(h4 + (size_t)d * BATCH + b);
    __syncthreads();
    dense_stage(A, B, p.wd1, p.bd1, 256, 512, true);
    dense_stage(B, A, p.wd2, p.bd2, 512, 256, true);
    dense_stage(A, B, p.wd3, p.bd3, 256, 128, true);
    dense_stage(B, A, p.wd4, p.bd4, 128, 64,  true);
    dense_stage(A, B, p.wd5, p.bd5, 64,  16,  true);
    dense_stage(B, A, p.wd6, p.bd6, 16,  3,   false);
    if (tid == 0) {
      float z0 = A[0], z1 = A[1], z2 = A[2];
      float m  = fmaxf(fmaxf(z0, z1), z2);
      float e0 = expf(z0 - m), e1 = expf(z1 - m), e2 = expf(z2 - m);
      float s  = e0 + e1 + e2;
      p.out[b * 3 + 0] = e0 / s;
      p.out[b * 3 + 1] = e1 / s;
      p.out[b * 3 + 2] = e2 / s;
    }
  }
}

// ---------------- launch ----------------
extern "C" void kernel_launch(void* const* d_in, const int* in_sizes, int n_in,
                              void* d_out, int out_size, void* d_ws, size_t ws_size,
                              hipStream_t stream) {
  KParams prm;
  prm.x  = (const float*)d_in[0];
  prm.k1 = (const float*)d_in[1];  prm.r1 = (const float*)d_in[2];  prm.b1 = (const float*)d_in[3];
  prm.k2 = (const float*)d_in[4];  prm.r2 = (const float*)d_in[5];  prm.b2 = (const float*)d_in[6];
  prm.k3 = (const float*)d_in[7];  prm.r3 = (const float*)d_in[8];  prm.b3 = (const float*)d_in[9];
  prm.k4 = (const float*)d_in[10]; prm.r4 = (const float*)d_in[11]; prm.b4 = (const float*)d_in[12];
  prm.wd1 = (const float*)d_in[13]; prm.bd1 = (const float*)d_in[14];
  prm.wd2 = (const float*)d_in[15]; prm.bd2 = (const float*)d_in[16];
  prm.wd3 = (const float*)d_in[17]; prm.bd3 = (const float*)d_in[18];
  prm.wd4 = (const float*)d_in[19]; prm.bd4 = (const float*)d_in[20];
  prm.wd5 = (const float*)d_in[21]; prm.bd5 = (const float*)d_in[22];
  prm.wd6 = (const float*)d_in[23]; prm.bd6 = (const float*)d_in[24];
  prm.out = (float*)d_out;
  prm.ws  = (float*)d_ws;

  // zero the barrier counter (must happen every launch; ws is poisoned 0xAA)
  hipMemsetAsync((char*)d_ws + O_CTR * 4, 0, 64, stream);

  void* args[] = { &prm };
  hipLaunchCooperativeKernel((void*)fused_kernel, dim3(NBLOCKS), dim3(NT),
                             args, 0, stream);
}

// Round 4
// 46633.209 us; speedup vs baseline: 1.4675x; 1.3352x over previous
//
#include <hip/hip_runtime.h>
#include <hip/hip_cooperative_groups.h>
#include <cstdint>
#include <cstddef>

namespace cg = cooperative_groups;

static constexpr int BATCH   = 128;
static constexpr int TSTEPS  = 512;
static constexpr int NBLOCKS = 244;   // <= 256 CUs -> co-residency guaranteed
static constexpr int NT      = 256;
static constexpr int CK      = 64;    // k-rows per staged chunk (32 KB)

// block role ranges
static constexpr int NB1 = 80, NB2 = 100, NB3 = 32, NB4 = 32;
static constexpr int RB2 = NB1, RB3 = NB1 + NB2, RB4 = NB1 + NB2 + NB3;

// ---------------- workspace layout (float offsets) ----------------
static constexpr size_t O_XT  = 0;                         // [512][64][128]
static constexpr size_t SZ_XT = 512ull * 64 * 128;
static constexpr size_t O_H1  = O_XT + SZ_XT;              // 2 parities x [H][128]
static constexpr size_t O_H2  = O_H1 + 2ull * 640 * 128;
static constexpr size_t O_H3  = O_H2 + 2ull * 400 * 128;
static constexpr size_t O_H4  = O_H3 + 2ull * 256 * 128;
static constexpr size_t O_HEND= O_H4 + 2ull * 256 * 128;
static constexpr size_t HTOT  = O_HEND - O_H1;
static constexpr size_t O_PK1 = O_HEND;                    // [80][704][8][4]
static constexpr size_t O_PK2 = O_PK1 + 80ull  * 704  * 8 * 4;   // [100][1040][4][4]
static constexpr size_t O_PK3 = O_PK2 + 100ull * 1040 * 4 * 4;   // [32][656][8][4]
static constexpr size_t O_PK4 = O_PK3 + 32ull  * 656  * 8 * 4;   // [32][512][8][4]
static constexpr size_t O_CTR = O_PK4 + 32ull  * 512  * 8 * 4;

struct KParams {
  const float *x;
  const float *k1, *r1, *b1, *k2, *r2, *b2, *k3, *r3, *b3, *k4, *r4, *b4;
  const float *wd1, *bd1, *wd2, *bd2, *wd3, *bd3, *wd4, *bd4, *wd5, *bd5, *wd6, *bd6;
  float *out;
  float *ws;
};

__device__ __forceinline__ void fma4(float4& a, float s, const float4& w) {
  a.x += s * w.x; a.y += s * w.y; a.z += s * w.z; a.w += s * w.w;
}
__device__ __forceinline__ float sigm(float v) { return 1.f / (1.f + expf(-v)); }

// ---- coherent (agent-scope) h exchange ----
__device__ __forceinline__ void h_store2(float* p, float a, float b) {
  union { float f[2]; unsigned long long u; } v; v.f[0] = a; v.f[1] = b;
  __hip_atomic_store((unsigned long long*)p, v.u, __ATOMIC_RELAXED, __HIP_MEMORY_SCOPE_AGENT);
}
__device__ __forceinline__ unsigned long long h_load8(const float* p) {
  return __hip_atomic_load((const unsigned long long*)p, __ATOMIC_RELAXED, __HIP_MEMORY_SCOPE_AGENT);
}
__device__ __forceinline__ float h_load1(const float* p) {
  return __hip_atomic_load(p, __ATOMIC_RELAXED, __HIP_MEMORY_SCOPE_AGENT);
}

// ---- light grid barrier: one atomicAdd/block + relaxed poll; no cache flush ----
__device__ __forceinline__ void light_barrier(unsigned* ctr, unsigned target) {
  asm volatile("s_waitcnt vmcnt(0)" ::: "memory");
  __syncthreads();
  if (threadIdx.x == 0) {
    __hip_atomic_fetch_add(ctr, 1u, __ATOMIC_RELAXED, __HIP_MEMORY_SCOPE_AGENT);
    while (__hip_atomic_load(ctr, __ATOMIC_RELAXED, __HIP_MEMORY_SCOPE_AGENT) < target) {
      __builtin_amdgcn_s_sleep(2);
    }
  }
  __syncthreads();
}

// ---------------- weight prepack: pack[blk][k][quad][gate] ----------------
__device__ void prepack_layer(const float* __restrict__ gk, const float* __restrict__ gr,
                              float* __restrict__ pack, int DIN, int H, int NJ, int NBLK,
                              int gtid, int gstr) {
  const long K = DIN + H;
  const long total = (long)NBLK * K * NJ * 4;
  for (long e = gtid; e < total; e += gstr) {
    int  g   = (int)(e & 3);
    long r   = e >> 2;
    int  q   = (int)(r % NJ);
    long r2  = r / NJ;
    int  k   = (int)(r2 % K);
    int  blk = (int)(r2 / K);
    int  j   = blk * NJ + q;
    float v = (k < DIN) ? gk[(size_t)k * 4 * H + (size_t)g * H + j]
                        : gr[(size_t)(k - DIN) * 4 * H + (size_t)g * H + j];
    pack[e] = v;
  }
}

// ---------------- persistent LSTM layer role (chunked LDS pipeline) ----------------
// Block covers NJ j-columns x all 128 batches, full-K reduction per thread.
// NJ*BG == 256; MB = 128/BG batches per thread.
template<int DIN, int H, int NJ, int BG, int LOFF, bool SEQIN>
__device__ __forceinline__ void lstm_role(int blk,
                          const float* __restrict__ xT,
                          const float* __restrict__ inH,
                          float* __restrict__ ownH,
                          const float* __restrict__ pack,
                          const float* __restrict__ gbias,
                          float* lds, unsigned* ctr) {
  constexpr int K   = DIN + H;
  constexpr int MB  = BATCH / BG;                 // 4 or 2
  constexpr int NCH = (K + CK - 1) / CK;
  constexpr int PPT = (CK * 64) / NT;             // 16 8-byte pairs per thread per chunk
  static_assert(NJ * BG == NT, "bad split");

  const int tid = threadIdx.x;
  const int jj  = tid / BG;
  const int bg  = tid % BG;
  const int b0  = bg * MB;
  const int j   = blk * NJ + jj;

  const float* mypack = pack + (size_t)blk * K * NJ * 4;
  const float4 bias = make_float4(gbias[j], gbias[H + j], gbias[2 * H + j], gbias[3 * H + j]);

  float c[MB];
  #pragma unroll
  for (int m = 0; m < MB; ++m) c[m] = 0.f;

  float* buf0 = lds;
  float* buf1 = lds + CK * BATCH;

  for (int s = 0; s < TSTEPS + 3; ++s) {
    const int t = s - LOFF;
    if (t >= 0 && t < TSTEPS) {
      const int par = (s - 1) & 1;
      const float* src_lo = SEQIN ? (xT + (size_t)t * DIN * BATCH)
                                  : (inH + (size_t)par * DIN * BATCH);
      const float* src_hi = ownH + (size_t)par * H * BATCH;

      float4 a[MB];
      #pragma unroll
      for (int m = 0; m < MB; ++m) a[m] = make_float4(0.f, 0.f, 0.f, 0.f);

      // ---- stage chunk 0 (burst: all loads issued before any use) ----
      unsigned long long tmp[PPT];
      #pragma unroll
      for (int r = 0; r < PPT; ++r) {
        const int p  = r * NT + tid;
        const int k  = p >> 6;
        const int bb = (p & 63) * 2;
        const float* sp = (k < DIN) ? (src_lo + (size_t)k * BATCH + bb)
                                    : (src_hi + (size_t)(k - DIN) * BATCH + bb);
        tmp[r] = h_load8(sp);
      }
      #pragma unroll
      for (int r = 0; r < PPT; ++r) {
        const int p = r * NT + tid;
        *(unsigned long long*)(buf0 + 2 * p) = tmp[r];
      }
      __syncthreads();

      for (int ch = 0; ch < NCH; ++ch) {
        float* cur = (ch & 1) ? buf1 : buf0;
        float* nxt = (ch & 1) ? buf0 : buf1;
        const int kb = ch * CK;
        const bool more = (ch + 1 < NCH);

        // issue next chunk's loads (burst, no uses in between)
        if (more) {
          const int kb2 = kb + CK;
          #pragma unroll
          for (int r = 0; r < PPT; ++r) {
            const int p  = r * NT + tid;
            const int k  = kb2 + (p >> 6);
            const int bb = (p & 63) * 2;
            if (k < K) {
              const float* sp = (k < DIN) ? (src_lo + (size_t)k * BATCH + bb)
                                          : (src_hi + (size_t)(k - DIN) * BATCH + bb);
              tmp[r] = h_load8(sp);
            } else tmp[r] = 0ull;
          }
        }

        // consume current chunk from LDS (hides next chunk's load latency)
        const int kmax = (K - kb < CK) ? (K - kb) : CK;
        const float* wrow = mypack + ((size_t)kb * NJ + jj) * 4;
        #pragma unroll 4
        for (int kl = 0; kl < kmax; ++kl) {
          float4 w = *(const float4*)(wrow + (size_t)kl * NJ * 4);
          if constexpr (MB == 4) {
            float4 hv = *(const float4*)(cur + kl * BATCH + b0);
            fma4(a[0], hv.x, w); fma4(a[1], hv.y, w);
            fma4(a[2], hv.z, w); fma4(a[3], hv.w, w);
          } else {
            float2 hv = *(const float2*)(cur + kl * BATCH + b0);
            fma4(a[0], hv.x, w); fma4(a[1], hv.y, w);
          }
        }

        // park next chunk into LDS
        if (more) {
          #pragma unroll
          for (int r = 0; r < PPT; ++r) {
            const int p = r * NT + tid;
            *(unsigned long long*)(nxt + 2 * p) = tmp[r];
          }
        }
        __syncthreads();
      }

      // ---- epilogue: gates, state update, coherent store ----
      float* dst = ownH + (size_t)(s & 1) * H * BATCH + (size_t)j * BATCH + b0;
      float hv[MB];
      #pragma unroll
      for (int m = 0; m < MB; ++m) {
        float ig = sigm(a[m].x + bias.x);
        float fg = sigm(a[m].y + bias.y);
        float gg = tanhf(a[m].z + bias.z);
        float og = sigm(a[m].w + bias.w);
        c[m] = fg * c[m] + ig * gg;
        hv[m] = og * tanhf(c[m]);
      }
      if constexpr (MB == 4) {
        h_store2(dst + 0, hv[0], hv[1]);
        h_store2(dst + 2, hv[2], hv[3]);
      } else {
        h_store2(dst, hv[0], hv[1]);
      }
    }
    light_barrier(ctr, (unsigned)(s + 1) * (unsigned)NBLOCKS);
  }
}

// ---------------- dense head helpers ----------------
__device__ void dense_stage(const float* in, float* outb,
                            const float* __restrict__ w, const float* __restrict__ bias,
                            int din, int dout, bool relu) {
  for (int jc = threadIdx.x; jc < dout; jc += NT) {
    float s = bias[jc];
    for (int d = 0; d < din; ++d) s += in[d] * w[(size_t)d * dout + jc];
    outb[jc] = relu ? fmaxf(s, 0.f) : s;
  }
  __syncthreads();
}

// ---------------- the fused cooperative kernel ----------------
__global__ __launch_bounds__(NT, 1) void fused_kernel(KParams p) {
  cg::grid_group grid = cg::this_grid();
  __shared__ float lds[2 * CK * BATCH];   // 64 KB

  float* ws  = p.ws;
  unsigned* ctr = (unsigned*)(ws + O_CTR);
  const int tid  = threadIdx.x;
  const int bid  = blockIdx.x;
  const int gtid = bid * NT + tid;
  const int gstr = NBLOCKS * NT;

  // ---- phase 0a: zero all h parity buffers ----
  {
    float* hb = ws + O_H1;
    for (size_t i = gtid; i < HTOT; i += gstr) hb[i] = 0.f;
  }
  // ---- phase 0b: prepack weights ----
  prepack_layer(p.k1, p.r1, ws + O_PK1, 64,  640, 8, NB1, gtid, gstr);
  prepack_layer(p.k2, p.r2, ws + O_PK2, 640, 400, 4, NB2, gtid, gstr);
  prepack_layer(p.k3, p.r3, ws + O_PK3, 400, 256, 8, NB3, gtid, gstr);
  prepack_layer(p.k4, p.r4, ws + O_PK4, 256, 256, 8, NB4, gtid, gstr);
  // ---- phase 0c: transpose x [128][512][64] -> xT [512][64][128] ----
  {
    float* tile = lds;                  // [64][129] padded = 33 KB
    float* xT   = ws + O_XT;
    for (int t = bid; t < TSTEPS; t += NBLOCKS) {
      int b = tid >> 1, dbase = (tid & 1) * 32;
      const float* src = p.x + ((size_t)b * TSTEPS + t) * 64 + dbase;
      #pragma unroll
      for (int q = 0; q < 8; ++q) {
        float4 v = *(const float4*)(src + 4 * q);
        tile[(dbase + 4 * q + 0) * 129 + b] = v.x;
        tile[(dbase + 4 * q + 1) * 129 + b] = v.y;
        tile[(dbase + 4 * q + 2) * 129 + b] = v.z;
        tile[(dbase + 4 * q + 3) * 129 + b] = v.w;
      }
      __syncthreads();
      int d = tid >> 2, bb = (tid & 3) * 32;
      float* dst = xT + ((size_t)t * 64 + d) * BATCH + bb;
      #pragma unroll
      for (int q = 0; q < 8; ++q) {
        float4 v = make_float4(tile[d * 129 + bb + 4 * q + 0],
                               tile[d * 129 + bb + 4 * q + 1],
                               tile[d * 129 + bb + 4 * q + 2],
                               tile[d * 129 + bb + 4 * q + 3]);
        *(float4*)(dst + 4 * q) = v;
      }
      __syncthreads();
    }
  }

  // ONE full CG sync: publishes xT/packs/zeroed-h everywhere
  grid.sync();

  // ---- phase 1: pipelined 4-layer LSTM scan ----
  if (bid < RB2) {
    lstm_role< 64, 640, 8, 32, 0, true >(bid,       ws + O_XT, nullptr,   ws + O_H1, ws + O_PK1, p.b1, lds, ctr);
  } else if (bid < RB3) {
    lstm_role<640, 400, 4, 64, 1, false>(bid - RB2, nullptr,  ws + O_H1, ws + O_H2, ws + O_PK2, p.b2, lds, ctr);
  } else if (bid < RB4) {
    lstm_role<400, 256, 8, 32, 2, false>(bid - RB3, nullptr,  ws + O_H2, ws + O_H3, ws + O_PK3, p.b3, lds, ctr);
  } else {
    lstm_role<256, 256, 8, 32, 3, false>(bid - RB4, nullptr,  ws + O_H3, ws + O_H4, ws + O_PK4, p.b4, lds, ctr);
  }

  // ---- phase 2: dense head (h4 final is parity 0; read agent-scope) ----
  if (bid < BATCH) {
    const int b = bid;
    float* A = lds;
    float* B = lds + 512;
    const float* h4 = ws + O_H4;
    for (int d = tid; d < 256; d += NT) A[d] = h_load1(h4 + (size_t)d * BATCH + b);
    __syncthreads();
    dense_stage(A, B, p.wd1, p.bd1, 256, 512, true);
    dense_stage(B, A, p.wd2, p.bd2, 512, 256, true);
    dense_stage(A, B, p.wd3, p.bd3, 256, 128, true);
    dense_stage(B, A, p.wd4, p.bd4, 128, 64,  true);
    dense_stage(A, B, p.wd5, p.bd5, 64,  16,  true);
    dense_stage(B, A, p.wd6, p.bd6, 16,  3,   false);
    if (tid == 0) {
      float z0 = A[0], z1 = A[1], z2 = A[2];
      float m  = fmaxf(fmaxf(z0, z1), z2);
      float e0 = expf(z0 - m), e1 = expf(z1 - m), e2 = expf(z2 - m);
      float s  = e0 + e1 + e2;
      p.out[b * 3 + 0] = e0 / s;
      p.out[b * 3 + 1] = e1 / s;
      p.out[b * 3 + 2] = e2 / s;
    }
  }
}

// ---------------- launch ----------------
extern "C" void kernel_launch(void* const* d_in, const int* in_sizes, int n_in,
                              void* d_out, int out_size, void* d_ws, size_t ws_size,
                              hipStream_t stream) {
  KParams prm;
  prm.x  = (const float*)d_in[0];
  prm.k1 = (const float*)d_in[1];  prm.r1 = (const float*)d_in[2];  prm.b1 = (const float*)d_in[3];
  prm.k2 = (const float*)d_in[4];  prm.r2 = (const float*)d_in[5];  prm.b2 = (const float*)d_in[6];
  prm.k3 = (const float*)d_in[7];  prm.r3 = (const float*)d_in[8];  prm.b3 = (const float*)d_in[9];
  prm.k4 = (const float*)d_in[10]; prm.r4 = (const float*)d_in[11]; prm.b4 = (const float*)d_in[12];
  prm.wd1 = (const float*)d_in[13]; prm.bd1 = (const float*)d_in[14];
  prm.wd2 = (const float*)d_in[15]; prm.bd2 = (const float*)d_in[16];
  prm.wd3 = (const float*)d_in[17]; prm.bd3 = (const float*)d_in[18];
  prm.wd4 = (const float*)d_in[19]; prm.bd4 = (const float*)d_in[20];
  prm.wd5 = (const float*)d_in[21]; prm.bd5 = (const float*)d_in[22];
  prm.wd6 = (const float*)d_in[23]; prm.bd6 = (const float*)d_in[24];
  prm.out = (float*)d_out;
  prm.ws  = (float*)d_ws;

  hipMemsetAsync((char*)d_ws + O_CTR * 4, 0, 64, stream);

  void* args[] = { &prm };
  hipLaunchCooperativeKernel((void*)fused_kernel, dim3(NBLOCKS), dim3(NT),
                             args, 0, stream);
}